// Round 12
// baseline (100.122 us; speedup 1.0000x reference)
//
#include <hip/hip_runtime.h>
#include <math.h>

#define RES_W 256
#define RES_H 256
#define TF_RES 128

typedef float float2u __attribute__((ext_vector_type(2), aligned(4)));

// One thread per ray, serial compositing, but loads issued 4 samples deep
// (phase-split unroll): 16 float2 loads in flight per wave -> 4x the MLP of
// the R11 serial loop, whose per-iteration exposed HBM latency was the wall.
__global__ __launch_bounds__(64) void raycast_kernel(
    const float* __restrict__ vol,    // [256,256,256] x-major: idx = (x<<16)+(y<<8)+z
    const float* __restrict__ tf,     // [128,4]
    const float* __restrict__ cam_p,  // [3]
    const int*   __restrict__ sr_p,   // [1]
    float* __restrict__ out)          // [256,256,5]  idx = (w*256+h)*5+c
{
    #pragma clang fp contract(off)

    // 129-entry SoA TF tables: [128] dups [127] so (lo,lo+1) is an adjacent
    // dword pair -> ds_read2_b32; exact at the lo==127 edge.
    __shared__ float tfR[TF_RES + 1], tfG[TF_RES + 1], tfB[TF_RES + 1], tfA[TF_RES + 1];
    const int tid = (int)threadIdx.x;          // 0..63
    {
        const float4* tf4 = (const float4*)tf;
        float4 e0 = tf4[tid];
        float4 e1 = tf4[tid + 64];
        tfR[tid] = e0.x; tfG[tid] = e0.y; tfB[tid] = e0.z; tfA[tid] = e0.w;
        tfR[tid + 64] = e1.x; tfG[tid + 64] = e1.y; tfB[tid + 64] = e1.z; tfA[tid + 64] = e1.w;
        if (tid == 63) {
            tfR[TF_RES] = e1.x; tfG[TF_RES] = e1.y; tfB[TF_RES] = e1.z; tfA[TF_RES] = e1.w;
        }
    }
    __syncthreads();

    // 1024 blocks x 64 threads; wave = 8x8 pixel tile (coherent gather front).
    // XCD swizzle: block b -> XCD b%8 gets a contiguous image slab.
    const int b    = (int)blockIdx.x;          // 0..1023
    const int tile = (b % 8) * 128 + (b / 8);  // 0..1023
    const int tile_h = tile % 32;
    const int tile_w = tile / 32;
    const int h = tile_h * 8 + (tid % 8);      // H index (v axis)
    const int w = tile_w * 8 + (tid / 8);      // W index (u axis)

    const float cx = cam_p[0], cy = cam_p[1], cz = cam_p[2];
    const int   sr_i = sr_p[0];
    const float srf = (float)sr_i;

    // ---- camera basis, fp32, numpy op order, no FMA (bit-matches reference) ----
    float nx = -cx, ny = -cy, nz = -cz;
    float fl = __fsqrt_rn((nx*nx + ny*ny) + nz*nz);
    float fx = nx / fl, fy = ny / fl, fz = nz / fl;
    float rxu = 0.0f - fz;
    float rzu = fx;
    float rl = __fsqrt_rn((rxu*rxu + 0.0f) + rzu*rzu);
    float rx = rxu / rl, rz = rzu / rl;
    float ux = 0.0f - rz*fy;
    float uy = rz*fx - rx*fz;
    float uz = rx*fy;

    const float ang32 = (float)((30.0 * 0.017453292519943295) * 0.5);
    const float tan_half = (float)tan((double)ang32);

    float uu = ((((float)w + 0.5f) / 256.0f) * 2.0f - 1.0f) * tan_half;
    float vv = ((((float)h + 0.5f) / 256.0f) * 2.0f - 1.0f) * tan_half;

    float dx = (fx + uu*rx) + vv*ux;
    float dy = (fy + 0.0f ) + vv*uy;
    float dz = (fz + uu*rz) + vv*uz;
    float dl = __fsqrt_rn((dx*dx + dy*dy) + dz*dz);
    dx = dx / dl; dy = dy / dl; dz = dz / dl;

    float ivx = 1.0f/dx, ivy = 1.0f/dy, ivz = 1.0f/dz;
    float tlx = (-1.0f - cx)*ivx, thx = (1.0f - cx)*ivx;
    float tly = (-1.0f - cy)*ivy, thy = (1.0f - cy)*ivy;
    float tlz = (-1.0f - cz)*ivz, thz = (1.0f - cz)*ivz;
    float tmin = fmaxf(fmaxf(fminf(tlx,thx), fminf(tly,thy)), fminf(tlz,thz));
    float tmax = fminf(fminf(fmaxf(tlx,thx), fmaxf(tly,thy)), fmaxf(tlz,thz));
    bool hit = (tmax >= 0.0f) && (tmin <= tmax);

    float entry = fmaxf(tmin, 0.1f);
    float dist  = hit ? fmaxf(tmax - entry, 0.0f) : 0.0f;
    float nsf   = fminf(fmaxf(ceilf(((dist * 0.5f) * 256.0f) * srf), 1.0f), 384.0f);
    int   ns    = (int)nsf;
    float step  = dist / nsf;

    float rgb_r = 0.0f, rgb_g = 0.0f, rgb_b = 0.0f, acc = 0.0f;
    float Texcl = 1.0f;
    float depth = 1.0f;
    bool  found = false;
    bool  done  = !hit;

    for (int base = 0; ; ) {
        if (!done) {
            // ---- phase A: 4 samples' positions + 16 z-pair loads in flight ----
            float t_[4], ffx_[4], ffy_[4], ffz_[4];
            float2u p00_[4], p10_[4], p01_[4], p11_[4];
            int z0_[4];
            #pragma unroll
            for (int j = 0; j < 4; ++j) {
                float t  = entry + ((float)(base + j) + 0.5f) * step;
                t_[j] = t;
                float px = (cx + t*dx);
                float py = (cy + t*dy);
                float pz = (cz + t*dz);
                px = ((px * 0.5f) + 0.5f) * 255.0f;
                py = ((py * 0.5f) + 0.5f) * 255.0f;
                pz = ((pz * 0.5f) + 0.5f) * 255.0f;
                px = fminf(fmaxf(px, 0.0f), 255.0f);
                py = fminf(fmaxf(py, 0.0f), 255.0f);
                pz = fminf(fmaxf(pz, 0.0f), 255.0f);
                int x0 = (int)px, y0 = (int)py, z0 = (int)pz;   // >=0: trunc==floor
                ffx_[j] = px - (float)x0;
                ffy_[j] = py - (float)y0;
                ffz_[j] = pz - (float)z0;
                z0_[j]  = z0;
                int x1 = min(x0 + 1, 255);
                int y1 = min(y0 + 1, 255);
                int zb = min(z0, 254);        // z-pair base; z0==255 -> ffz==0 exactly
                int bx0 = x0 << 16, bx1 = x1 << 16;
                int by0 = y0 << 8,  by1 = y1 << 8;
                p00_[j] = *(const float2u*)(vol + (bx0 + by0 + zb));
                p10_[j] = *(const float2u*)(vol + (bx1 + by0 + zb));
                p01_[j] = *(const float2u*)(vol + (bx0 + by1 + zb));
                p11_[j] = *(const float2u*)(vol + (bx1 + by1 + zb));
            }
            // ---- phase B: sequential compositing, bit-identical to reference ----
            #pragma unroll
            for (int j = 0; j < 4; ++j) {
                if (!done && (base + j) < ns) {
                    float2u p00 = p00_[j], p10 = p10_[j], p01 = p01_[j], p11 = p11_[j];
                    if (z0_[j] == 255) {      // tap z0 must read index 255 = pair.y
                        p00.x = p00.y; p10.x = p10.y; p01.x = p01.y; p11.x = p11.y;
                    }
                    float omx = 1.0f - ffx_[j], omy = 1.0f - ffy_[j], omz = 1.0f - ffz_[j];
                    float c00 = p00.x*omx + p10.x*ffx_[j];
                    float c10 = p01.x*omx + p11.x*ffx_[j];
                    float c01 = p00.y*omx + p10.y*ffx_[j];
                    float c11 = p01.y*omx + p11.y*ffx_[j];
                    float c0  = c00*omy + c10*ffy_[j];
                    float c1  = c01*omy + c11*ffy_[j];
                    float intensity = c0*omz + c1*ffz_[j];

                    float xi = fminf(fmaxf(intensity, 0.0f), 1.0f) * 127.0f;
                    int lo  = (int)xi;
                    float tfr = xi - (float)lo;
                    float omt = 1.0f - tfr;
                    float cr  = tfR[lo]*omt + tfR[lo + 1]*tfr;
                    float cg  = tfG[lo]*omt + tfG[lo + 1]*tfr;
                    float cbb = tfB[lo]*omt + tfB[lo + 1]*tfr;
                    float a   = tfA[lo]*omt + tfA[lo + 1]*tfr;

                    if (sr_i == 1) {
                        a = 1.0f - (1.0f - a);        // double rounding, as numpy
                    } else {
                        a = 1.0f - powf(1.0f - a, 1.0f / srf);
                    }
                    float one_m = 1.0f - a;
                    float wgt = Texcl * a;
                    rgb_r += wgt * cr;
                    rgb_g += wgt * cg;
                    rgb_b += wgt * cbb;
                    acc   += wgt;
                    if (!found && a > 1e-3f) {
                        found = true;
                        depth = (t_[j] - 0.1f) / 99.9f;
                    }
                    Texcl = Texcl * one_m;
                    // T<2e-3 implies some a>1e-3 already seen (depth set);
                    // dropped tail <= 2e-3 per channel — inside error budget.
                    if (Texcl < 2e-3f) done = true;
                }
            }
            base += 4;
            if (base >= ns) done = true;
        }
        if (__ballot(!done) == 0ULL) break;
    }

    {
        int oi = (w * RES_H + h) * 5;
        out[oi + 0] = rgb_r;
        out[oi + 1] = rgb_g;
        out[oi + 2] = rgb_b;
        out[oi + 3] = acc;
        out[oi + 4] = depth;
    }
}

extern "C" void kernel_launch(void* const* d_in, const int* in_sizes, int n_in,
                              void* d_out, int out_size, void* d_ws, size_t ws_size,
                              hipStream_t stream) {
    const float* vol = (const float*)d_in[0];
    const float* tf  = (const float*)d_in[1];
    const float* cam = (const float*)d_in[2];
    const int*   sr  = (const int*)d_in[3];
    float* out = (float*)d_out;

    raycast_kernel<<<dim3(1024), dim3(64), 0, stream>>>(vol, tf, cam, sr, out);
}